// Round 7
// baseline (776.276 us; speedup 1.0000x reference)
//
#include <hip/hip_runtime.h>
#include <math.h>
#include <stdint.h>

#define N_NODES 50000
#define N_EDGES 1600000
#define IN_C    1433
#define HID_C   128
#define OUT_C   47
#define KPAD1   1440

typedef unsigned short u16;

// float -> bf16 (RNE), also returns the bf16 value re-expanded to float
__device__ inline u16 f2bf(float x, float& hf) {
    unsigned u = __float_as_uint(x);
    unsigned r = (u + 0x7FFFu + ((u >> 16) & 1u)) & 0xFFFF0000u;
    hf = __uint_as_float(r);
    return (u16)(r >> 16);
}

// async global->LDS, 16B per lane. LDS dest = wave-uniform base + lane*16;
// global src is per-lane (so swizzles are applied on the SOURCE address).
__device__ inline void gld_lds16(const void* g, const void* lds) {
    __builtin_amdgcn_global_load_lds(
        (const __attribute__((address_space(1))) unsigned int*)(unsigned long long)(uintptr_t)g,
        (__attribute__((address_space(3))) unsigned int*)(unsigned long long)(unsigned)(uintptr_t)lds,
        16, 0, 0);
}

__device__ inline void wg_barrier() {
    asm volatile("" ::: "memory");
    __builtin_amdgcn_s_barrier();
    asm volatile("" ::: "memory");
}

// ---------------- utility ----------------
__global__ __launch_bounds__(256) void k_zero_i(int* p, int n) {
    int i = blockIdx.x * 256 + threadIdx.x;
    if (i < n) p[i] = 0;
}

__global__ __launch_bounds__(256) void k_count(const int* __restrict__ dst, int* __restrict__ cnt) {
    int e = blockIdx.x * 256 + threadIdx.x;
    if (e < N_EDGES) atomicAdd(&cnt[dst[e]], 1);
}

__global__ __launch_bounds__(256) void k_dinv(const int* __restrict__ cnt, float* __restrict__ dinv) {
    int i = blockIdx.x * 256 + threadIdx.x;
    if (i < N_NODES) dinv[i] = rsqrtf(1.0f + (float)cnt[i]);
}

__global__ __launch_bounds__(1024) void k_scan(const int* __restrict__ cnt, int* __restrict__ row_start) {
    __shared__ int sums[1024];
    const int t = threadIdx.x;
    const int CH = (N_NODES + 1023) / 1024;
    const int base = t * CH;
    int s = 0;
    for (int j = 0; j < CH; ++j) { int idx = base + j; if (idx < N_NODES) s += cnt[idx]; }
    sums[t] = s;
    __syncthreads();
    for (int off = 1; off < 1024; off <<= 1) {
        int v = (t >= off) ? sums[t - off] : 0;
        __syncthreads();
        sums[t] += v;
        __syncthreads();
    }
    int run = (t == 0) ? 0 : sums[t - 1];
    for (int j = 0; j < CH; ++j) {
        int idx = base + j;
        if (idx < N_NODES) { row_start[idx] = run; run += cnt[idx]; }
    }
    if (t == 1023) row_start[N_NODES] = N_EDGES;
}

__global__ __launch_bounds__(256) void k_fill(
    const int* __restrict__ src, const int* __restrict__ dst,
    const int* __restrict__ row_start, int* __restrict__ cursor,
    int* __restrict__ csr_src)
{
    int e = blockIdx.x * 256 + threadIdx.x;
    if (e >= N_EDGES) return;
    int t = dst[e];
    int pos = row_start[t] + atomicAdd(&cursor[t], 1);
    csr_src[pos] = src[e];
}

// W [K][N=128] fp32 -> WT_hi/lo [128][Kpad] bf16 (zero-padded K)
__global__ __launch_bounds__(256) void k_wsplit(
    const float* __restrict__ W, int K, int Kpad,
    u16* __restrict__ Thi, u16* __restrict__ Tlo)
{
    int id = blockIdx.x * 256 + threadIdx.x;
    if (id >= 128 * Kpad) return;
    int n = id / Kpad, k = id - n * Kpad;
    float v = (k < K) ? W[(long)k * HID_C + n] : 0.f;
    float hf; u16 h = f2bf(v, hf);
    float d;  u16 l = f2bf(v - hf, d);
    Thi[id] = h; Tlo[id] = l;
}

// ---------------- A-in-registers / B-LDS-pipelined MFMA GEMM, N fixed = 128 ----------------
// C[M,128] = f(A)[M,K] @ B[K,128] via 3-term bf16 split (error ~2^-17).
// vs round 6: A never touches LDS. Each wave's fragment rows are wave-private
// (wave pairs dedup via L1): A(t+1) is loaded to REGISTERS (scalar dwords,
// ping-pong buffers, compiler-managed precise waits). LDS holds only B
// (3 x 16 KB = 48 KB -> 3 blocks/CU, matching the 782-block grid), staged
// depth-2 via global_load_lds + counted vmcnt; never drained to 0 in-loop.
// Per step: issue A(t+1) regs + B(t+2) DMA; vmcnt(24) keeps
// B(t+1)+A(t+1)+B(t+2) in flight; barrier; convert+MFMA; barrier.
template<bool RELU_A>
__global__ __launch_bounds__(256) void k_gemm_mfma(
    const float* __restrict__ A, const u16* __restrict__ BThi,
    const u16* __restrict__ BTlo, float* __restrict__ C,
    int M, int K, int Kpad, int lda)
{
    using bf16x8 = __attribute__((ext_vector_type(8))) short;
    using f32x4  = __attribute__((ext_vector_type(4))) float;

    __shared__ u16 Bhs[3][4096];   // [128 rows][32 k] bf16-hi, chunk-swizzled
    __shared__ u16 Bls[3][4096];   // [128 rows][32 k] bf16-lo

    const int tid  = threadIdx.x;
    const int wave = tid >> 6, lane = tid & 63;
    const int lr   = lane & 15, quad = lane >> 4;
    const int wm   = (wave >> 1) * 32, wn = (wave & 1) * 64;
    const int m0   = blockIdx.x * 64;
    const int kq   = quad * 8;

    int rr0 = m0 + wm + lr;      if (rr0 >= M) rr0 = M - 1;   // clamp: rows unstored
    int rr1 = m0 + wm + 16 + lr; if (rr1 >= M) rr1 = M - 1;
    const float* a0 = A + (long)rr0 * lda;
    const float* a1 = A + (long)rr1 * lda;

    f32x4 acc[2][4];
#pragma unroll
    for (int i = 0; i < 2; ++i)
#pragma unroll
        for (int j = 0; j < 4; ++j)
#pragma unroll
            for (int r = 0; r < 4; ++r) acc[i][j][r] = 0.f;

    const int nk = (K + 31) >> 5;

    // B slab for step t: 128 rows x 64 B (hi) + same (lo). 2 instr/wave each.
    // stored chunk g: row=g>>2, c=g&3 holds logical chunk q = c ^ ((row>>1)&3).
    auto stageB = [&](int t, int buf) {
        const int k0 = t * 32;
#pragma unroll
        for (int i = 0; i < 2; ++i) {
            const int gc  = wave * 128 + i * 64;
            const int g   = gc + lane;
            const int row = g >> 2, c = g & 3;
            const int q   = c ^ ((row >> 1) & 3);
            const long goff = (long)row * Kpad + k0 + q * 8;
            gld_lds16(BThi + goff, &Bhs[buf][gc * 8]);
            gld_lds16(BTlo + goff, &Bls[buf][gc * 8]);
        }
    };

    // A fragments for step t -> registers (16 scalar dword loads; rows are
    // only 4B-aligned at lda=1433 so no vector proof possible; issue-once,
    // compiler inserts precise vmcnt before first use).
    auto loadA = [&](int t, float (&v)[16]) {
        const int k0 = t * 32 + kq;
        if (t * 32 + 32 <= K) {
#pragma unroll
            for (int i = 0; i < 8; ++i) { v[i] = a0[k0 + i]; v[8 + i] = a1[k0 + i]; }
        } else {
#pragma unroll
            for (int i = 0; i < 8; ++i) {
                const int gk = k0 + i;
                v[i]     = (gk < K) ? a0[gk] : 0.f;
                v[8 + i] = (gk < K) ? a1[gk] : 0.f;
            }
        }
    };

    auto compute = [&](int buf, float (&cur)[16]) {
        bf16x8 ah[2], al[2];
#pragma unroll
        for (int i = 0; i < 2; ++i) {
#pragma unroll
            for (int c = 0; c < 8; ++c) {
                float x = cur[i * 8 + c];
                if (RELU_A) x = fmaxf(x, 0.f);
                float hf; u16 h = f2bf(x, hf);
                float d;  u16 l = f2bf(x - hf, d);
                ah[i][c] = (short)h; al[i][c] = (short)l;
            }
        }
        bf16x8 bh[4], bl[4];
#pragma unroll
        for (int j = 0; j < 4; ++j) {
            const int row = wn + j * 16 + lr;
            const int cs  = quad ^ ((row >> 1) & 3);
            bh[j] = *(const bf16x8*)&Bhs[buf][row * 32 + cs * 8];
            bl[j] = *(const bf16x8*)&Bls[buf][row * 32 + cs * 8];
        }
#pragma unroll
        for (int i = 0; i < 2; ++i)
#pragma unroll
            for (int j = 0; j < 4; ++j) {
                acc[i][j] = __builtin_amdgcn_mfma_f32_16x16x32_bf16(ah[i], bh[j], acc[i][j], 0, 0, 0);
                acc[i][j] = __builtin_amdgcn_mfma_f32_16x16x32_bf16(ah[i], bl[j], acc[i][j], 0, 0, 0);
                acc[i][j] = __builtin_amdgcn_mfma_f32_16x16x32_bf16(al[i], bh[j], acc[i][j], 0, 0, 0);
            }
    };

    float vA0[16], vA1[16];

    // prologue (issue order matters for vmcnt counting): B(0), A(0), B(1)
    stageB(0, 0);
    loadA(0, vA0);
    if (nk > 1) stageB(1, 1);

    // per-step wait: drain through A(t) (and thus B(t), older), keep
    // B(t+1)[4] + A(t+1)[16] + B(t+2)[4] = 24 in flight.
#define GEMM_WAIT(s)                                                        \
    do {                                                                    \
        if ((s) + 2 < nk)      asm volatile("s_waitcnt vmcnt(24)" ::: "memory"); \
        else if ((s) + 1 < nk) asm volatile("s_waitcnt vmcnt(20)" ::: "memory"); \
        else                   asm volatile("s_waitcnt vmcnt(0)"  ::: "memory"); \
    } while (0)

    int t = 0;
    for (; t + 1 < nk; t += 2) {
        // even step: consume vA0, prefetch into vA1
        loadA(t + 1, vA1);
        if (t + 2 < nk) stageB(t + 2, (t + 2) % 3);
        GEMM_WAIT(t);
        wg_barrier();
        compute(t % 3, vA0);
        wg_barrier();
        // odd step: consume vA1, prefetch into vA0
        if (t + 2 < nk) loadA(t + 2, vA0);
        if (t + 3 < nk) stageB(t + 3, (t + 3) % 3);
        GEMM_WAIT(t + 1);
        wg_barrier();
        compute((t + 1) % 3, vA1);
        wg_barrier();
    }
    if (t < nk) {   // odd nk tail: consume vA0
        GEMM_WAIT(t);
        wg_barrier();
        compute(t % 3, vA0);
    }
#undef GEMM_WAIT

    // ---- store: C/D layout col=lane&15, row=quad*4+reg ----
#pragma unroll
    for (int i = 0; i < 2; ++i)
#pragma unroll
        for (int r = 0; r < 4; ++r) {
            int row = m0 + wm + i * 16 + quad * 4 + r;
            if (row < M) {
#pragma unroll
                for (int j = 0; j < 4; ++j)
                    C[(long)row * HID_C + wn + j * 16 + lr] = acc[i][j][r];
            }
        }
}

// ---------------- fp32 tiled GEMM (kept for the small 128x47 layer) ----------------
template<int BN, bool RELU_A, bool BIAS>
__global__ __launch_bounds__(256) void k_gemm(
    const float* __restrict__ A, const float* __restrict__ B,
    const float* __restrict__ bias, float* __restrict__ C,
    int M, int N, int K, int lda, int ldb, int ldc)
{
    constexpr int BM = 64, BK = 16;
    constexpr int TNV = BN / 64;
    __shared__ float As[BK][BM + 4];
    __shared__ float Bs[BK][BN];

    const int tid = threadIdx.x;
    const int tm = tid >> 4;
    const int tn = tid & 15;
    const int m0 = blockIdx.x * BM;
    const int n0 = blockIdx.y * BN;

    float acc[4][TNV * 4];
#pragma unroll
    for (int r = 0; r < 4; ++r)
#pragma unroll
        for (int c = 0; c < TNV * 4; ++c) acc[r][c] = 0.f;

    for (int k0 = 0; k0 < K; k0 += BK) {
        {
            int kk = tid & 15;
            int r0 = tid >> 4;
#pragma unroll
            for (int it = 0; it < 4; ++it) {
                int r = r0 + 16 * it;
                int gm = m0 + r, gk = k0 + kk;
                float v = 0.f;
                if (gm < M && gk < K) v = A[(long)gm * lda + gk];
                if (RELU_A) v = fmaxf(v, 0.f);
                As[kk][r] = v;
            }
        }
        {
            constexpr int KPP = 256 / BN;
            int n  = tid % BN;
            int kb = tid / BN;
#pragma unroll
            for (int it = 0; it < BK / KPP; ++it) {
                int kk = kb + KPP * it;
                int gk = k0 + kk, gn = n0 + n;
                float v = 0.f;
                if (gk < K && gn < N) v = B[(long)gk * ldb + gn];
                Bs[kk][n] = v;
            }
        }
        __syncthreads();
#pragma unroll
        for (int kk = 0; kk < BK; ++kk) {
            float4 a = *(const float4*)&As[kk][tm * 4];
            float av[4] = {a.x, a.y, a.z, a.w};
#pragma unroll
            for (int j = 0; j < TNV; ++j) {
                float4 b = *(const float4*)&Bs[kk][tn * 4 + 64 * j];
                float bv[4] = {b.x, b.y, b.z, b.w};
#pragma unroll
                for (int r = 0; r < 4; ++r)
#pragma unroll
                    for (int c = 0; c < 4; ++c)
                        acc[r][c + j * 4] += av[r] * bv[c];
            }
        }
        __syncthreads();
    }
#pragma unroll
    for (int r = 0; r < 4; ++r) {
        int gm = m0 + tm * 4 + r;
        if (gm >= M) continue;
#pragma unroll
        for (int j = 0; j < TNV; ++j)
#pragma unroll
            for (int c = 0; c < 4; ++c) {
                int gn = n0 + tn * 4 + 64 * j + c;
                if (gn < N) {
                    float v = acc[r][c + j * 4];
                    if (BIAS) v += bias[gn];
                    C[(long)gm * ldc + gn] = v;
                }
            }
    }
}

// ---------------- CSR gather-aggregate, 128-dim (float2 x 64 lanes) ----------------
template<bool RELU_IN, bool BIAS>
__global__ __launch_bounds__(256) void k_aggregate(
    const float2* __restrict__ hw, const int* __restrict__ row_start,
    const int* __restrict__ csr_src, const float* __restrict__ dinv,
    const float* __restrict__ bias, float2* __restrict__ out)
{
    const int tid = threadIdx.x;
    const int node = blockIdx.x * 4 + (tid >> 6);
    if (node >= N_NODES) return;
    const int lane = tid & 63;

    float dt = dinv[node];
    float2 v = hw[(long)node * 64 + lane];
    if (RELU_IN) { v.x = fmaxf(v.x, 0.f); v.y = fmaxf(v.y, 0.f); }
    float2 acc = {0.f, 0.f};

    const int e1 = row_start[node + 1];
    int e = row_start[node];
    for (; e + 2 <= e1; e += 2) {
        int s0 = csr_src[e], s1 = csr_src[e + 1];
        float w0 = dinv[s0], w1 = dinv[s1];
        float2 u0 = hw[(long)s0 * 64 + lane];
        float2 u1 = hw[(long)s1 * 64 + lane];
        if (RELU_IN) {
            u0.x = fmaxf(u0.x, 0.f); u0.y = fmaxf(u0.y, 0.f);
            u1.x = fmaxf(u1.x, 0.f); u1.y = fmaxf(u1.y, 0.f);
        }
        acc.x += w0 * u0.x + w1 * u1.x;
        acc.y += w0 * u0.y + w1 * u1.y;
    }
    if (e < e1) {
        int s0 = csr_src[e];
        float w0 = dinv[s0];
        float2 u0 = hw[(long)s0 * 64 + lane];
        if (RELU_IN) { u0.x = fmaxf(u0.x, 0.f); u0.y = fmaxf(u0.y, 0.f); }
        acc.x += w0 * u0.x;
        acc.y += w0 * u0.y;
    }

    float2 r;
    r.x = dt * (acc.x + dt * v.x);
    r.y = dt * (acc.y + dt * v.y);
    if (BIAS) {
        float2 b = ((const float2*)bias)[lane];
        r.x += b.x; r.y += b.y;
    }
    out[(long)node * 64 + lane] = r;
}

// ---------------- CSR gather-aggregate, 47-dim (projected layer 3) ----------------
// hw rows padded to 48 floats (192 B = 3 aligned cache lines per gather).
__global__ __launch_bounds__(256) void k_aggregate47(
    const float* __restrict__ hw, const int* __restrict__ row_start,
    const int* __restrict__ csr_src, const float* __restrict__ dinv,
    const float* __restrict__ bias, float* __restrict__ out)
{
    const int tid = threadIdx.x;
    const int node = blockIdx.x * 4 + (tid >> 6);
    if (node >= N_NODES) return;
    const int lane = tid & 63;
    if (lane >= OUT_C) return;   // no barriers below; pad column 47 never touched

    float dt = dinv[node];
    float v = hw[(long)node * 48 + lane];
    float acc = 0.f;

    const int e1 = row_start[node + 1];
    int e = row_start[node];
    for (; e + 2 <= e1; e += 2) {
        int s0 = csr_src[e], s1 = csr_src[e + 1];
        float w0 = dinv[s0], w1 = dinv[s1];
        float u0 = hw[(long)s0 * 48 + lane];
        float u1 = hw[(long)s1 * 48 + lane];
        acc += w0 * u0 + w1 * u1;
    }
    if (e < e1) {
        int s0 = csr_src[e];
        acc += dinv[s0] * hw[(long)s0 * 48 + lane];
    }

    out[(long)node * OUT_C + lane] = dt * (acc + dt * v) + bias[lane];
}

extern "C" void kernel_launch(void* const* d_in, const int* in_sizes, int n_in,
                              void* d_out, int out_size, void* d_ws, size_t ws_size,
                              hipStream_t stream) {
    const float* x  = (const float*)d_in[0];
    const int*   ei = (const int*)  d_in[1];
    const float* W1 = (const float*)d_in[2];
    const float* b1 = (const float*)d_in[3];
    const float* W2 = (const float*)d_in[4];
    const float* b2 = (const float*)d_in[5];
    const float* W3 = (const float*)d_in[6];
    const float* b3 = (const float*)d_in[7];
    float* out = (float*)d_out;
    const int* src = ei;
    const int* dst = ei + N_EDGES;

    char* ws = (char*)d_ws;
    float* dinv      = (float*)(ws + 0);
    int*   cnt       = (int*)  (ws + 200192);
    int*   cursor    = (int*)  (ws + 400384);
    int*   row_start = (int*)  (ws + 600576);
    int*   csr_src   = (int*)  (ws + 801280);
    float* bufA      = (float*)(ws + 7201280);
    float* bufB      = (float*)(ws + 32801280);
    u16*   W1Thi     = (u16*)  (ws + 58401280);   // 128*1440*2 = 368640
    u16*   W1Tlo     = (u16*)  (ws + 58769920);
    u16*   W2Thi     = (u16*)  (ws + 59138560);   // 128*128*2 = 32768
    u16*   W2Tlo     = (u16*)  (ws + 59171328);   // ends 59204096 (~59.2 MB)

    dim3 blk(256);
    const int gN  = (N_NODES + 255) / 256;
    const int gE  = (N_EDGES + 255) / 256;
    const int gAg = (N_NODES + 3) / 4;
    const int gMf = (N_NODES + 63) / 64;          // 782 blocks, 3/CU (48 KB LDS)
    dim3 gGemm((N_NODES + 63) / 64, 1);

    // ---- CSR build + norm ----
    k_zero_i<<<gN, blk, 0, stream>>>(cnt, N_NODES);
    k_zero_i<<<gN, blk, 0, stream>>>(cursor, N_NODES);
    k_count<<<gE, blk, 0, stream>>>(dst, cnt);
    k_dinv<<<gN, blk, 0, stream>>>(cnt, dinv);
    k_scan<<<1, 1024, 0, stream>>>(cnt, row_start);
    k_fill<<<gE, blk, 0, stream>>>(src, dst, row_start, cursor, csr_src);

    // ---- weight split/transpose ----
    k_wsplit<<<(128 * KPAD1 + 255) / 256, blk, 0, stream>>>(W1, IN_C, KPAD1, W1Thi, W1Tlo);
    k_wsplit<<<(128 * HID_C + 255) / 256, blk, 0, stream>>>(W2, HID_C, HID_C, W2Thi, W2Tlo);

    // ---- layer 1 ----
    k_gemm_mfma<false><<<gMf, blk, 0, stream>>>(x, W1Thi, W1Tlo, bufA, N_NODES, IN_C, KPAD1, IN_C);
    k_aggregate<false, true><<<gAg, blk, 0, stream>>>(
        (const float2*)bufA, row_start, csr_src, dinv, b1, (float2*)bufB);

    // ---- layer 2 ----
    k_gemm_mfma<true><<<gMf, blk, 0, stream>>>(bufB, W2Thi, W2Tlo, bufA, N_NODES, HID_C, HID_C, HID_C);
    k_aggregate<false, true><<<gAg, blk, 0, stream>>>(
        (const float2*)bufA, row_start, csr_src, dinv, b2, (float2*)bufB);

    // ---- layer 3: project first (A·(relu(h2)W3) == (A·relu(h2))W3), then 47-dim aggregate ----
    k_gemm<64, true, false><<<gGemm, blk, 0, stream>>>(
        bufB, W3, nullptr, bufA, N_NODES, OUT_C, HID_C, HID_C, OUT_C, 48);
    k_aggregate47<<<gAg, blk, 0, stream>>>(
        bufA, row_start, csr_src, dinv, b3, out);
}

// Round 8
// 696.654 us; speedup vs baseline: 1.1143x; 1.1143x over previous
//
#include <hip/hip_runtime.h>
#include <math.h>
#include <stdint.h>

#define N_NODES 50000
#define N_EDGES 1600000
#define IN_C    1433
#define HID_C   128
#define OUT_C   47
#define KPAD1   1440

typedef unsigned short u16;

// float -> bf16 (RNE), also returns the bf16 value re-expanded to float
__device__ inline u16 f2bf(float x, float& hf) {
    unsigned u = __float_as_uint(x);
    unsigned r = (u + 0x7FFFu + ((u >> 16) & 1u)) & 0xFFFF0000u;
    hf = __uint_as_float(r);
    return (u16)(r >> 16);
}

// async global->LDS, 16B per lane. LDS dest = wave-uniform base + lane*16;
// global src is per-lane (so swizzles are applied on the SOURCE address).
__device__ inline void gld_lds16(const void* g, const void* lds) {
    __builtin_amdgcn_global_load_lds(
        (const __attribute__((address_space(1))) unsigned int*)(unsigned long long)(uintptr_t)g,
        (__attribute__((address_space(3))) unsigned int*)(unsigned long long)(unsigned)(uintptr_t)lds,
        16, 0, 0);
}

__device__ inline void wg_barrier() {
    asm volatile("" ::: "memory");
    __builtin_amdgcn_s_barrier();
    asm volatile("" ::: "memory");
}

// ---------------- utility ----------------
__global__ __launch_bounds__(256) void k_zero_i(int* p, int n) {
    int i = blockIdx.x * 256 + threadIdx.x;
    if (i < n) p[i] = 0;
}

__global__ __launch_bounds__(256) void k_count(const int* __restrict__ dst, int* __restrict__ cnt) {
    int e = blockIdx.x * 256 + threadIdx.x;
    if (e < N_EDGES) atomicAdd(&cnt[dst[e]], 1);
}

__global__ __launch_bounds__(256) void k_dinv(const int* __restrict__ cnt, float* __restrict__ dinv) {
    int i = blockIdx.x * 256 + threadIdx.x;
    if (i < N_NODES) dinv[i] = rsqrtf(1.0f + (float)cnt[i]);
}

__global__ __launch_bounds__(1024) void k_scan(const int* __restrict__ cnt, int* __restrict__ row_start) {
    __shared__ int sums[1024];
    const int t = threadIdx.x;
    const int CH = (N_NODES + 1023) / 1024;
    const int base = t * CH;
    int s = 0;
    for (int j = 0; j < CH; ++j) { int idx = base + j; if (idx < N_NODES) s += cnt[idx]; }
    sums[t] = s;
    __syncthreads();
    for (int off = 1; off < 1024; off <<= 1) {
        int v = (t >= off) ? sums[t - off] : 0;
        __syncthreads();
        sums[t] += v;
        __syncthreads();
    }
    int run = (t == 0) ? 0 : sums[t - 1];
    for (int j = 0; j < CH; ++j) {
        int idx = base + j;
        if (idx < N_NODES) { row_start[idx] = run; run += cnt[idx]; }
    }
    if (t == 1023) row_start[N_NODES] = N_EDGES;
}

__global__ __launch_bounds__(256) void k_fill(
    const int* __restrict__ src, const int* __restrict__ dst,
    const int* __restrict__ row_start, int* __restrict__ cursor,
    int* __restrict__ csr_src)
{
    int e = blockIdx.x * 256 + threadIdx.x;
    if (e >= N_EDGES) return;
    int t = dst[e];
    int pos = row_start[t] + atomicAdd(&cursor[t], 1);
    csr_src[pos] = src[e];
}

// W [K][N=128] fp32 -> WT_hi/lo [128][Kpad] bf16 (zero-padded K)
__global__ __launch_bounds__(256) void k_wsplit(
    const float* __restrict__ W, int K, int Kpad,
    u16* __restrict__ Thi, u16* __restrict__ Tlo)
{
    int id = blockIdx.x * 256 + threadIdx.x;
    if (id >= 128 * Kpad) return;
    int n = id / Kpad, k = id - n * Kpad;
    float v = (k < K) ? W[(long)k * HID_C + n] : 0.f;
    float hf; u16 h = f2bf(v, hf);
    float d;  u16 l = f2bf(v - hf, d);
    Thi[id] = h; Tlo[id] = l;
}

// ---------------- depth-2 pipelined LDS-staged MFMA GEMM, N fixed = 128 ----------------
// (round-6 version, best measured: 161.9 us on layer 1)
// Per step: issue stage(t+2); s_waitcnt vmcnt(12) (waits own stage(t) only --
// t+1/t+2 stay IN FLIGHT across the barrier, never drain to 0 in the loop);
// s_barrier; ds_read/convert/MFMA; s_barrier. LDS 72 KB -> 2 blocks/CU.
template<bool RELU_A>
__global__ __launch_bounds__(256) void k_gemm_mfma(
    const float* __restrict__ A, const u16* __restrict__ BThi,
    const u16* __restrict__ BTlo, float* __restrict__ C,
    int M, int K, int Kpad, int lda)
{
    using bf16x8 = __attribute__((ext_vector_type(8))) short;
    using f32x4  = __attribute__((ext_vector_type(4))) float;

    __shared__ float Af[3][2048];   // [64 rows][32 k] fp32, 16B-chunk-swizzled
    __shared__ u16  Bhs[3][4096];   // [128 rows][32 k] bf16-hi, chunk-swizzled
    __shared__ u16  Bls[3][4096];   // [128 rows][32 k] bf16-lo

    const int tid  = threadIdx.x;
    const int wave = tid >> 6, lane = tid & 63;
    const int lr   = lane & 15, quad = lane >> 4;
    const int wm   = (wave >> 1) * 32, wn = (wave & 1) * 64;
    const int m0   = blockIdx.x * 64;

    f32x4 acc[2][4];
#pragma unroll
    for (int i = 0; i < 2; ++i)
#pragma unroll
        for (int j = 0; j < 4; ++j)
#pragma unroll
            for (int r = 0; r < 4; ++r) acc[i][j][r] = 0.f;

    const int nk = (K + 31) >> 5;

    // B slab for step t: 128 rows x 64 B (hi) + same (lo). 2 instr/wave each.
    // stored chunk g: row=g>>2, c=g&3 holds logical chunk q = c ^ ((row>>1)&3).
    auto stageB = [&](int t, int buf) {
        const int k0 = t * 32;
#pragma unroll
        for (int i = 0; i < 2; ++i) {
            const int gc  = wave * 128 + i * 64;
            const int g   = gc + lane;
            const int row = g >> 2, c = g & 3;
            const int q   = c ^ ((row >> 1) & 3);
            const long goff = (long)row * Kpad + k0 + q * 8;
            gld_lds16(BThi + goff, &Bhs[buf][gc * 8]);
            gld_lds16(BTlo + goff, &Bls[buf][gc * 8]);
        }
    };
    // A slab for step t: 64 rows x 128 B fp32. stored chunk g: row=g>>3,
    // c=g&7 holds logical chunk q = c ^ (row&7). Ragged last step falls back
    // to predicated register staging (ends with lgkmcnt(0): raw barriers
    // do NOT auto-drain LDS writes).
    auto stageA = [&](int t, int buf) {
        const int k0 = t * 32;
        if (k0 + 32 <= K) {
#pragma unroll
            for (int i = 0; i < 2; ++i) {
                const int gc  = wave * 128 + i * 64;
                const int g   = gc + lane;
                const int row = g >> 3, c = g & 7;
                const int q   = c ^ (row & 7);
                int gm = m0 + row; if (gm >= M) gm = M - 1;   // clamp: rows unstored
                gld_lds16(A + (long)gm * lda + k0 + q * 4, &Af[buf][gc * 4]);
            }
        } else {
#pragma unroll
            for (int i = 0; i < 2; ++i) {
                const int g   = wave * 128 + i * 64 + lane;
                const int row = g >> 3, c = g & 7;
                const int q   = c ^ (row & 7);
                int gm = m0 + row; if (gm >= M) gm = M - 1;
                const float* p = A + (long)gm * lda;
                const int kb = k0 + q * 4;
                float4 v;
                v.x = (kb + 0 < K) ? p[kb + 0] : 0.f;
                v.y = (kb + 1 < K) ? p[kb + 1] : 0.f;
                v.z = (kb + 2 < K) ? p[kb + 2] : 0.f;
                v.w = (kb + 3 < K) ? p[kb + 3] : 0.f;
                *(float4*)&Af[buf][g * 4] = v;
            }
            asm volatile("s_waitcnt lgkmcnt(0)" ::: "memory");
        }
    };

    // prologue: 2 slabs in flight, NO drain
    stageA(0, 0); stageB(0, 0);
    if (nk > 1) { stageA(1, 1); stageB(1, 1); }

    for (int t = 0; t < nk; ++t) {
        const int buf = t % 3;
        if (t + 2 < nk) {
            const int nb = (t + 2) % 3;
            stageA(t + 2, nb); stageB(t + 2, nb);
            asm volatile("s_waitcnt vmcnt(12)" ::: "memory");   // own stage(t) done
        } else if (t + 1 < nk) {
            asm volatile("s_waitcnt vmcnt(6)" ::: "memory");
        } else {
            asm volatile("s_waitcnt vmcnt(0)" ::: "memory");
        }
        wg_barrier();   // all waves' stage(t) complete -> buf readable

        // ---- A fragments from LDS, convert fp32 -> hi/lo bf16 in-register ----
        bf16x8 ah[2], al[2];
#pragma unroll
        for (int i = 0; i < 2; ++i) {
            const int row = wm + i * 16 + lr;
            const int rx  = row & 7;
            f32x4 x0 = *(const f32x4*)&Af[buf][row * 32 + (((2 * quad)     ^ rx) * 4)];
            f32x4 x1 = *(const f32x4*)&Af[buf][row * 32 + (((2 * quad + 1) ^ rx) * 4)];
            float a8[8] = {x0[0], x0[1], x0[2], x0[3], x1[0], x1[1], x1[2], x1[3]};
#pragma unroll
            for (int c = 0; c < 8; ++c) {
                float x = RELU_A ? fmaxf(a8[c], 0.f) : a8[c];
                float hf; u16 h = f2bf(x, hf);
                float d;  u16 l = f2bf(x - hf, d);
                ah[i][c] = (short)h; al[i][c] = (short)l;
            }
        }
        // ---- B fragments from LDS ----
        bf16x8 bh[4], bl[4];
#pragma unroll
        for (int j = 0; j < 4; ++j) {
            const int row = wn + j * 16 + lr;
            const int cs  = quad ^ ((row >> 1) & 3);
            bh[j] = *(const bf16x8*)&Bhs[buf][row * 32 + cs * 8];
            bl[j] = *(const bf16x8*)&Bls[buf][row * 32 + cs * 8];
        }
#pragma unroll
        for (int i = 0; i < 2; ++i)
#pragma unroll
            for (int j = 0; j < 4; ++j) {
                acc[i][j] = __builtin_amdgcn_mfma_f32_16x16x32_bf16(ah[i], bh[j], acc[i][j], 0, 0, 0);
                acc[i][j] = __builtin_amdgcn_mfma_f32_16x16x32_bf16(ah[i], bl[j], acc[i][j], 0, 0, 0);
                acc[i][j] = __builtin_amdgcn_mfma_f32_16x16x32_bf16(al[i], bh[j], acc[i][j], 0, 0, 0);
            }
        wg_barrier();   // all waves done reading buf -> reusable at t+3
    }

    // ---- store: C/D layout col=lane&15, row=quad*4+reg ----
#pragma unroll
    for (int i = 0; i < 2; ++i)
#pragma unroll
        for (int r = 0; r < 4; ++r) {
            int row = m0 + wm + i * 16 + quad * 4 + r;
            if (row < M) {
#pragma unroll
                for (int j = 0; j < 4; ++j)
                    C[(long)row * HID_C + wn + j * 16 + lr] = acc[i][j][r];
            }
        }
}

// ---------------- fp32 tiled GEMM (kept for the small 128x47 layer) ----------------
template<int BN, bool RELU_A, bool BIAS>
__global__ __launch_bounds__(256) void k_gemm(
    const float* __restrict__ A, const float* __restrict__ B,
    const float* __restrict__ bias, float* __restrict__ C,
    int M, int N, int K, int lda, int ldb, int ldc)
{
    constexpr int BM = 64, BK = 16;
    constexpr int TNV = BN / 64;
    __shared__ float As[BK][BM + 4];
    __shared__ float Bs[BK][BN];

    const int tid = threadIdx.x;
    const int tm = tid >> 4;
    const int tn = tid & 15;
    const int m0 = blockIdx.x * BM;
    const int n0 = blockIdx.y * BN;

    float acc[4][TNV * 4];
#pragma unroll
    for (int r = 0; r < 4; ++r)
#pragma unroll
        for (int c = 0; c < TNV * 4; ++c) acc[r][c] = 0.f;

    for (int k0 = 0; k0 < K; k0 += BK) {
        {
            int kk = tid & 15;
            int r0 = tid >> 4;
#pragma unroll
            for (int it = 0; it < 4; ++it) {
                int r = r0 + 16 * it;
                int gm = m0 + r, gk = k0 + kk;
                float v = 0.f;
                if (gm < M && gk < K) v = A[(long)gm * lda + gk];
                if (RELU_A) v = fmaxf(v, 0.f);
                As[kk][r] = v;
            }
        }
        {
            constexpr int KPP = 256 / BN;
            int n  = tid % BN;
            int kb = tid / BN;
#pragma unroll
            for (int it = 0; it < BK / KPP; ++it) {
                int kk = kb + KPP * it;
                int gk = k0 + kk, gn = n0 + n;
                float v = 0.f;
                if (gk < K && gn < N) v = B[(long)gk * ldb + gn];
                Bs[kk][n] = v;
            }
        }
        __syncthreads();
#pragma unroll
        for (int kk = 0; kk < BK; ++kk) {
            float4 a = *(const float4*)&As[kk][tm * 4];
            float av[4] = {a.x, a.y, a.z, a.w};
#pragma unroll
            for (int j = 0; j < TNV; ++j) {
                float4 b = *(const float4*)&Bs[kk][tn * 4 + 64 * j];
                float bv[4] = {b.x, b.y, b.z, b.w};
#pragma unroll
                for (int r = 0; r < 4; ++r)
#pragma unroll
                    for (int c = 0; c < 4; ++c)
                        acc[r][c + j * 4] += av[r] * bv[c];
            }
        }
        __syncthreads();
    }
#pragma unroll
    for (int r = 0; r < 4; ++r) {
        int gm = m0 + tm * 4 + r;
        if (gm >= M) continue;
#pragma unroll
        for (int j = 0; j < TNV; ++j)
#pragma unroll
            for (int c = 0; c < 4; ++c) {
                int gn = n0 + tn * 4 + 64 * j + c;
                if (gn < N) {
                    float v = acc[r][c + j * 4];
                    if (BIAS) v += bias[gn];
                    C[(long)gm * ldc + gn] = v;
                }
            }
    }
}

// ---------------- CSR gather-aggregate, 128-dim (float2 x 64 lanes) ----------------
// Unroll-4: 4 row-gathers + 4 dinv loads in flight per iteration (latency-bound
// gather -> double the MLP at zero byte cost).
template<bool RELU_IN, bool BIAS>
__global__ __launch_bounds__(256) void k_aggregate(
    const float2* __restrict__ hw, const int* __restrict__ row_start,
    const int* __restrict__ csr_src, const float* __restrict__ dinv,
    const float* __restrict__ bias, float2* __restrict__ out)
{
    const int tid = threadIdx.x;
    const int node = blockIdx.x * 4 + (tid >> 6);
    if (node >= N_NODES) return;
    const int lane = tid & 63;

    float dt = dinv[node];
    float2 v = hw[(long)node * 64 + lane];
    if (RELU_IN) { v.x = fmaxf(v.x, 0.f); v.y = fmaxf(v.y, 0.f); }
    float2 acc = {0.f, 0.f};

    const int e1 = row_start[node + 1];
    int e = row_start[node];
    for (; e + 4 <= e1; e += 4) {
        int s0 = csr_src[e],     s1 = csr_src[e + 1];
        int s2 = csr_src[e + 2], s3 = csr_src[e + 3];
        float w0 = dinv[s0], w1 = dinv[s1], w2 = dinv[s2], w3 = dinv[s3];
        float2 u0 = hw[(long)s0 * 64 + lane];
        float2 u1 = hw[(long)s1 * 64 + lane];
        float2 u2 = hw[(long)s2 * 64 + lane];
        float2 u3 = hw[(long)s3 * 64 + lane];
        if (RELU_IN) {
            u0.x = fmaxf(u0.x, 0.f); u0.y = fmaxf(u0.y, 0.f);
            u1.x = fmaxf(u1.x, 0.f); u1.y = fmaxf(u1.y, 0.f);
            u2.x = fmaxf(u2.x, 0.f); u2.y = fmaxf(u2.y, 0.f);
            u3.x = fmaxf(u3.x, 0.f); u3.y = fmaxf(u3.y, 0.f);
        }
        acc.x += w0 * u0.x + w1 * u1.x + w2 * u2.x + w3 * u3.x;
        acc.y += w0 * u0.y + w1 * u1.y + w2 * u2.y + w3 * u3.y;
    }
    for (; e + 2 <= e1; e += 2) {
        int s0 = csr_src[e], s1 = csr_src[e + 1];
        float w0 = dinv[s0], w1 = dinv[s1];
        float2 u0 = hw[(long)s0 * 64 + lane];
        float2 u1 = hw[(long)s1 * 64 + lane];
        if (RELU_IN) {
            u0.x = fmaxf(u0.x, 0.f); u0.y = fmaxf(u0.y, 0.f);
            u1.x = fmaxf(u1.x, 0.f); u1.y = fmaxf(u1.y, 0.f);
        }
        acc.x += w0 * u0.x + w1 * u1.x;
        acc.y += w0 * u0.y + w1 * u1.y;
    }
    if (e < e1) {
        int s0 = csr_src[e];
        float w0 = dinv[s0];
        float2 u0 = hw[(long)s0 * 64 + lane];
        if (RELU_IN) { u0.x = fmaxf(u0.x, 0.f); u0.y = fmaxf(u0.y, 0.f); }
        acc.x += w0 * u0.x;
        acc.y += w0 * u0.y;
    }

    float2 r;
    r.x = dt * (acc.x + dt * v.x);
    r.y = dt * (acc.y + dt * v.y);
    if (BIAS) {
        float2 b = ((const float2*)bias)[lane];
        r.x += b.x; r.y += b.y;
    }
    out[(long)node * 64 + lane] = r;
}

// ---------------- CSR gather-aggregate, 47-dim (projected layer 3) ----------------
// hw rows padded to 48 floats (192 B = 3 aligned cache lines per gather).
__global__ __launch_bounds__(256) void k_aggregate47(
    const float* __restrict__ hw, const int* __restrict__ row_start,
    const int* __restrict__ csr_src, const float* __restrict__ dinv,
    const float* __restrict__ bias, float* __restrict__ out)
{
    const int tid = threadIdx.x;
    const int node = blockIdx.x * 4 + (tid >> 6);
    if (node >= N_NODES) return;
    const int lane = tid & 63;
    if (lane >= OUT_C) return;   // no barriers below; pad column 47 never touched

    float dt = dinv[node];
    float v = hw[(long)node * 48 + lane];
    float acc = 0.f;

    const int e1 = row_start[node + 1];
    int e = row_start[node];
    for (; e + 4 <= e1; e += 4) {
        int s0 = csr_src[e],     s1 = csr_src[e + 1];
        int s2 = csr_src[e + 2], s3 = csr_src[e + 3];
        float w0 = dinv[s0], w1 = dinv[s1], w2 = dinv[s2], w3 = dinv[s3];
        float u0 = hw[(long)s0 * 48 + lane];
        float u1 = hw[(long)s1 * 48 + lane];
        float u2 = hw[(long)s2 * 48 + lane];
        float u3 = hw[(long)s3 * 48 + lane];
        acc += w0 * u0 + w1 * u1 + w2 * u2 + w3 * u3;
    }
    for (; e + 2 <= e1; e += 2) {
        int s0 = csr_src[e], s1 = csr_src[e + 1];
        float w0 = dinv[s0], w1 = dinv[s1];
        float u0 = hw[(long)s0 * 48 + lane];
        float u1 = hw[(long)s1 * 48 + lane];
        acc += w0 * u0 + w1 * u1;
    }
    if (e < e1) {
        int s0 = csr_src[e];
        acc += dinv[s0] * hw[(long)s0 * 48 + lane];
    }

    out[(long)node * OUT_C + lane] = dt * (acc + dt * v) + bias[lane];
}

extern "C" void kernel_launch(void* const* d_in, const int* in_sizes, int n_in,
                              void* d_out, int out_size, void* d_ws, size_t ws_size,
                              hipStream_t stream) {
    const float* x  = (const float*)d_in[0];
    const int*   ei = (const int*)  d_in[1];
    const float* W1 = (const float*)d_in[2];
    const float* b1 = (const float*)d_in[3];
    const float* W2 = (const float*)d_in[4];
    const float* b2 = (const float*)d_in[5];
    const float* W3 = (const float*)d_in[6];
    const float* b3 = (const float*)d_in[7];
    float* out = (float*)d_out;
    const int* src = ei;
    const int* dst = ei + N_EDGES;

    char* ws = (char*)d_ws;
    float* dinv      = (float*)(ws + 0);
    int*   cnt       = (int*)  (ws + 200192);
    int*   cursor    = (int*)  (ws + 400384);
    int*   row_start = (int*)  (ws + 600576);
    int*   csr_src   = (int*)  (ws + 801280);
    float* bufA      = (float*)(ws + 7201280);
    float* bufB      = (float*)(ws + 32801280);
    u16*   W1Thi     = (u16*)  (ws + 58401280);   // 128*1440*2 = 368640
    u16*   W1Tlo     = (u16*)  (ws + 58769920);
    u16*   W2Thi     = (u16*)  (ws + 59138560);   // 128*128*2 = 32768
    u16*   W2Tlo     = (u16*)  (ws + 59171328);   // ends 59204096 (~59.2 MB)

    dim3 blk(256);
    const int gN  = (N_NODES + 255) / 256;
    const int gE  = (N_EDGES + 255) / 256;
    const int gAg = (N_NODES + 3) / 4;
    const int gMf = (N_NODES + 63) / 64;          // 782 blocks, 2/CU (72 KB LDS)
    dim3 gGemm((N_NODES + 63) / 64, 1);

    // ---- CSR build + norm ----
    k_zero_i<<<gN, blk, 0, stream>>>(cnt, N_NODES);
    k_zero_i<<<gN, blk, 0, stream>>>(cursor, N_NODES);
    k_count<<<gE, blk, 0, stream>>>(dst, cnt);
    k_dinv<<<gN, blk, 0, stream>>>(cnt, dinv);
    k_scan<<<1, 1024, 0, stream>>>(cnt, row_start);
    k_fill<<<gE, blk, 0, stream>>>(src, dst, row_start, cursor, csr_src);

    // ---- weight split/transpose ----
    k_wsplit<<<(128 * KPAD1 + 255) / 256, blk, 0, stream>>>(W1, IN_C, KPAD1, W1Thi, W1Tlo);
    k_wsplit<<<(128 * HID_C + 255) / 256, blk, 0, stream>>>(W2, HID_C, HID_C, W2Thi, W2Tlo);

    // ---- layer 1 ----
    k_gemm_mfma<false><<<gMf, blk, 0, stream>>>(x, W1Thi, W1Tlo, bufA, N_NODES, IN_C, KPAD1, IN_C);
    k_aggregate<false, true><<<gAg, blk, 0, stream>>>(
        (const float2*)bufA, row_start, csr_src, dinv, b1, (float2*)bufB);

    // ---- layer 2 ----
    k_gemm_mfma<true><<<gMf, blk, 0, stream>>>(bufB, W2Thi, W2Tlo, bufA, N_NODES, HID_C, HID_C, HID_C);
    k_aggregate<false, true><<<gAg, blk, 0, stream>>>(
        (const float2*)bufA, row_start, csr_src, dinv, b2, (float2*)bufB);

    // ---- layer 3: project first (A·(relu(h2)W3) == (A·relu(h2))W3), then 47-dim aggregate ----
    k_gemm<64, true, false><<<gGemm, blk, 0, stream>>>(
        bufB, W3, nullptr, bufA, N_NODES, OUT_C, HID_C, HID_C, OUT_C, 48);
    k_aggregate47<<<gAg, blk, 0, stream>>>(
        bufA, row_start, csr_src, dinv, b3, out);
}

// Round 9
// 694.798 us; speedup vs baseline: 1.1173x; 1.0027x over previous
//
#include <hip/hip_runtime.h>
#include <math.h>
#include <stdint.h>

#define N_NODES 50000
#define N_EDGES 1600000
#define IN_C    1433
#define HID_C   128
#define OUT_C   47
#define KPAD1   1440

typedef unsigned short u16;

// float -> bf16 (RNE), also returns the bf16 value re-expanded to float
__device__ inline u16 f2bf(float x, float& hf) {
    unsigned u = __float_as_uint(x);
    unsigned r = (u + 0x7FFFu + ((u >> 16) & 1u)) & 0xFFFF0000u;
    hf = __uint_as_float(r);
    return (u16)(r >> 16);
}

// async global->LDS, 16B per lane. LDS dest = wave-uniform base + lane*16;
// global src is per-lane (so swizzles are applied on the SOURCE address).
__device__ inline void gld_lds16(const void* g, const void* lds) {
    __builtin_amdgcn_global_load_lds(
        (const __attribute__((address_space(1))) unsigned int*)(unsigned long long)(uintptr_t)g,
        (__attribute__((address_space(3))) unsigned int*)(unsigned long long)(unsigned)(uintptr_t)lds,
        16, 0, 0);
}

__device__ inline void wg_barrier() {
    asm volatile("" ::: "memory");
    __builtin_amdgcn_s_barrier();
    asm volatile("" ::: "memory");
}

// ---------------- utility ----------------
__global__ __launch_bounds__(256) void k_zero_i(int* p, int n) {
    int i = blockIdx.x * 256 + threadIdx.x;
    if (i < n) p[i] = 0;
}

__global__ __launch_bounds__(256) void k_count(const int* __restrict__ dst, int* __restrict__ cnt) {
    int e = blockIdx.x * 256 + threadIdx.x;
    if (e < N_EDGES) atomicAdd(&cnt[dst[e]], 1);
}

__global__ __launch_bounds__(256) void k_dinv(const int* __restrict__ cnt, float* __restrict__ dinv) {
    int i = blockIdx.x * 256 + threadIdx.x;
    if (i < N_NODES) dinv[i] = rsqrtf(1.0f + (float)cnt[i]);
}

__global__ __launch_bounds__(1024) void k_scan(const int* __restrict__ cnt, int* __restrict__ row_start) {
    __shared__ int sums[1024];
    const int t = threadIdx.x;
    const int CH = (N_NODES + 1023) / 1024;
    const int base = t * CH;
    int s = 0;
    for (int j = 0; j < CH; ++j) { int idx = base + j; if (idx < N_NODES) s += cnt[idx]; }
    sums[t] = s;
    __syncthreads();
    for (int off = 1; off < 1024; off <<= 1) {
        int v = (t >= off) ? sums[t - off] : 0;
        __syncthreads();
        sums[t] += v;
        __syncthreads();
    }
    int run = (t == 0) ? 0 : sums[t - 1];
    for (int j = 0; j < CH; ++j) {
        int idx = base + j;
        if (idx < N_NODES) { row_start[idx] = run; run += cnt[idx]; }
    }
    if (t == 1023) row_start[N_NODES] = N_EDGES;
}

__global__ __launch_bounds__(256) void k_fill(
    const int* __restrict__ src, const int* __restrict__ dst,
    const int* __restrict__ row_start, int* __restrict__ cursor,
    int* __restrict__ csr_src)
{
    int e = blockIdx.x * 256 + threadIdx.x;
    if (e >= N_EDGES) return;
    int t = dst[e];
    int pos = row_start[t] + atomicAdd(&cursor[t], 1);
    csr_src[pos] = src[e];
}

// W [K][N=128] fp32 -> WT_hi/lo [128][Kpad] bf16 (zero-padded K)
__global__ __launch_bounds__(256) void k_wsplit(
    const float* __restrict__ W, int K, int Kpad,
    u16* __restrict__ Thi, u16* __restrict__ Tlo)
{
    int id = blockIdx.x * 256 + threadIdx.x;
    if (id >= 128 * Kpad) return;
    int n = id / Kpad, k = id - n * Kpad;
    float v = (k < K) ? W[(long)k * HID_C + n] : 0.f;
    float hf; u16 h = f2bf(v, hf);
    float d;  u16 l = f2bf(v - hf, d);
    Thi[id] = h; Tlo[id] = l;
}

// ---------------- A-depth-3 / B-depth-2 pipelined MFMA GEMM, N fixed = 128 ----------------
// C[M,128] = f(A)[M,K] @ B[K,128] via 3-term bf16 split (error ~2^-17).
// vs round 6/8: A staged 3 steps ahead (4-buffer rotation) since A is the
// HBM-latency term (wall = latency/depth); B (L2-resident) stays depth-2
// (3 buffers). LDS = 4x8 KB (A) + 3x(8+8) KB (B) = exactly 80 KB -> still
// 2 blocks/CU. vmcnt ladder (queue-order verified, prologue A0,A1,B0,A2,B1;
// per step issue A(t+3) then B(t+2)): full=12, t+3==nk -> 10, t+2==nk -> 4,
// last -> 0. Buffer safety: writer of any buffer is >=1 end-of-step barrier
// after its last reader.
template<bool RELU_A>
__global__ __launch_bounds__(256) void k_gemm_mfma(
    const float* __restrict__ A, const u16* __restrict__ BThi,
    const u16* __restrict__ BTlo, float* __restrict__ C,
    int M, int K, int Kpad, int lda)
{
    using bf16x8 = __attribute__((ext_vector_type(8))) short;
    using f32x4  = __attribute__((ext_vector_type(4))) float;

    __shared__ float Af[4][2048];   // [64 rows][32 k] fp32, 16B-chunk-swizzled (32 KB)
    __shared__ u16  Bhs[3][4096];   // [128 rows][32 k] bf16-hi, chunk-swizzled (24 KB)
    __shared__ u16  Bls[3][4096];   // [128 rows][32 k] bf16-lo (24 KB)

    const int tid  = threadIdx.x;
    const int wave = tid >> 6, lane = tid & 63;
    const int lr   = lane & 15, quad = lane >> 4;
    const int wm   = (wave >> 1) * 32, wn = (wave & 1) * 64;
    const int m0   = blockIdx.x * 64;

    f32x4 acc[2][4];
#pragma unroll
    for (int i = 0; i < 2; ++i)
#pragma unroll
        for (int j = 0; j < 4; ++j)
#pragma unroll
            for (int r = 0; r < 4; ++r) acc[i][j][r] = 0.f;

    const int nk = (K + 31) >> 5;

    // B slab for step t: 128 rows x 64 B (hi) + same (lo). 4 vmcnt ops/wave.
    // stored chunk g: row=g>>2, c=g&3 holds logical chunk q = c ^ ((row>>1)&3).
    auto stageB = [&](int t, int buf) {
        const int k0 = t * 32;
#pragma unroll
        for (int i = 0; i < 2; ++i) {
            const int gc  = wave * 128 + i * 64;
            const int g   = gc + lane;
            const int row = g >> 2, c = g & 3;
            const int q   = c ^ ((row >> 1) & 3);
            const long goff = (long)row * Kpad + k0 + q * 8;
            gld_lds16(BThi + goff, &Bhs[buf][gc * 8]);
            gld_lds16(BTlo + goff, &Bls[buf][gc * 8]);
        }
    };
    // A slab for step t: 64 rows x 128 B fp32, 2 vmcnt ops/wave. stored chunk
    // g: row=g>>3, c=g&7 holds logical chunk q = c ^ (row&7). Ragged last step
    // falls back to predicated register staging (compiler inserts its own
    // vmcnt before the ds_writes -> one extra drain on 1 of 45 steps; ends
    // with lgkmcnt(0) since raw barriers don't auto-drain LDS writes).
    auto stageA = [&](int t, int buf) {
        const int k0 = t * 32;
        if (k0 + 32 <= K) {
#pragma unroll
            for (int i = 0; i < 2; ++i) {
                const int gc  = wave * 128 + i * 64;
                const int g   = gc + lane;
                const int row = g >> 3, c = g & 7;
                const int q   = c ^ (row & 7);
                int gm = m0 + row; if (gm >= M) gm = M - 1;   // clamp: rows unstored
                gld_lds16(A + (long)gm * lda + k0 + q * 4, &Af[buf][gc * 4]);
            }
        } else {
#pragma unroll
            for (int i = 0; i < 2; ++i) {
                const int g   = wave * 128 + i * 64 + lane;
                const int row = g >> 3, c = g & 7;
                const int q   = c ^ (row & 7);
                int gm = m0 + row; if (gm >= M) gm = M - 1;
                const float* p = A + (long)gm * lda;
                const int kb = k0 + q * 4;
                float4 v;
                v.x = (kb + 0 < K) ? p[kb + 0] : 0.f;
                v.y = (kb + 1 < K) ? p[kb + 1] : 0.f;
                v.z = (kb + 2 < K) ? p[kb + 2] : 0.f;
                v.w = (kb + 3 < K) ? p[kb + 3] : 0.f;
                *(float4*)&Af[buf][g * 4] = v;
            }
            asm volatile("s_waitcnt lgkmcnt(0)" ::: "memory");
        }
    };

    // prologue (issue order defines the vmcnt queue): A0, A1, B0, A2, B1
    stageA(0, 0);
    if (nk > 1) stageA(1, 1);
    stageB(0, 0);
    if (nk > 2) stageA(2, 2);
    if (nk > 1) stageB(1, 1);

    for (int t = 0; t < nk; ++t) {
        const int ba = t & 3, bb = t % 3;
        if (t + 3 < nk) {
            stageA(t + 3, (t + 3) & 3);
            stageB(t + 2, (t + 2) % 3);
            asm volatile("s_waitcnt vmcnt(12)" ::: "memory");  // A(t),B(t) done
        } else if (t + 3 == nk) {
            stageB(t + 2, (t + 2) % 3);
            asm volatile("s_waitcnt vmcnt(10)" ::: "memory");
        } else if (t + 2 == nk) {
            asm volatile("s_waitcnt vmcnt(4)" ::: "memory");
        } else {
            asm volatile("s_waitcnt vmcnt(0)" ::: "memory");
        }
        wg_barrier();   // all waves' stage(t) complete -> buffers readable

        // ---- A fragments from LDS, convert fp32 -> hi/lo bf16 in-register ----
        bf16x8 ah[2], al[2];
#pragma unroll
        for (int i = 0; i < 2; ++i) {
            const int row = wm + i * 16 + lr;
            const int rx  = row & 7;
            f32x4 x0 = *(const f32x4*)&Af[ba][row * 32 + (((2 * quad)     ^ rx) * 4)];
            f32x4 x1 = *(const f32x4*)&Af[ba][row * 32 + (((2 * quad + 1) ^ rx) * 4)];
            float a8[8] = {x0[0], x0[1], x0[2], x0[3], x1[0], x1[1], x1[2], x1[3]};
#pragma unroll
            for (int c = 0; c < 8; ++c) {
                float x = RELU_A ? fmaxf(a8[c], 0.f) : a8[c];
                float hf; u16 h = f2bf(x, hf);
                float d;  u16 l = f2bf(x - hf, d);
                ah[i][c] = (short)h; al[i][c] = (short)l;
            }
        }
        // ---- B fragments from LDS ----
        bf16x8 bh[4], bl[4];
#pragma unroll
        for (int j = 0; j < 4; ++j) {
            const int row = wn + j * 16 + lr;
            const int cs  = quad ^ ((row >> 1) & 3);
            bh[j] = *(const bf16x8*)&Bhs[bb][row * 32 + cs * 8];
            bl[j] = *(const bf16x8*)&Bls[bb][row * 32 + cs * 8];
        }
#pragma unroll
        for (int i = 0; i < 2; ++i)
#pragma unroll
            for (int j = 0; j < 4; ++j) {
                acc[i][j] = __builtin_amdgcn_mfma_f32_16x16x32_bf16(ah[i], bh[j], acc[i][j], 0, 0, 0);
                acc[i][j] = __builtin_amdgcn_mfma_f32_16x16x32_bf16(ah[i], bl[j], acc[i][j], 0, 0, 0);
                acc[i][j] = __builtin_amdgcn_mfma_f32_16x16x32_bf16(al[i], bh[j], acc[i][j], 0, 0, 0);
            }
        wg_barrier();   // all waves done reading -> buffers reusable
    }

    // ---- store: C/D layout col=lane&15, row=quad*4+reg ----
#pragma unroll
    for (int i = 0; i < 2; ++i)
#pragma unroll
        for (int r = 0; r < 4; ++r) {
            int row = m0 + wm + i * 16 + quad * 4 + r;
            if (row < M) {
#pragma unroll
                for (int j = 0; j < 4; ++j)
                    C[(long)row * HID_C + wn + j * 16 + lr] = acc[i][j][r];
            }
        }
}

// ---------------- fp32 tiled GEMM (kept for the small 128x47 layer) ----------------
template<int BN, bool RELU_A, bool BIAS>
__global__ __launch_bounds__(256) void k_gemm(
    const float* __restrict__ A, const float* __restrict__ B,
    const float* __restrict__ bias, float* __restrict__ C,
    int M, int N, int K, int lda, int ldb, int ldc)
{
    constexpr int BM = 64, BK = 16;
    constexpr int TNV = BN / 64;
    __shared__ float As[BK][BM + 4];
    __shared__ float Bs[BK][BN];

    const int tid = threadIdx.x;
    const int tm = tid >> 4;
    const int tn = tid & 15;
    const int m0 = blockIdx.x * BM;
    const int n0 = blockIdx.y * BN;

    float acc[4][TNV * 4];
#pragma unroll
    for (int r = 0; r < 4; ++r)
#pragma unroll
        for (int c = 0; c < TNV * 4; ++c) acc[r][c] = 0.f;

    for (int k0 = 0; k0 < K; k0 += BK) {
        {
            int kk = tid & 15;
            int r0 = tid >> 4;
#pragma unroll
            for (int it = 0; it < 4; ++it) {
                int r = r0 + 16 * it;
                int gm = m0 + r, gk = k0 + kk;
                float v = 0.f;
                if (gm < M && gk < K) v = A[(long)gm * lda + gk];
                if (RELU_A) v = fmaxf(v, 0.f);
                As[kk][r] = v;
            }
        }
        {
            constexpr int KPP = 256 / BN;
            int n  = tid % BN;
            int kb = tid / BN;
#pragma unroll
            for (int it = 0; it < BK / KPP; ++it) {
                int kk = kb + KPP * it;
                int gk = k0 + kk, gn = n0 + n;
                float v = 0.f;
                if (gk < K && gn < N) v = B[(long)gk * ldb + gn];
                Bs[kk][n] = v;
            }
        }
        __syncthreads();
#pragma unroll
        for (int kk = 0; kk < BK; ++kk) {
            float4 a = *(const float4*)&As[kk][tm * 4];
            float av[4] = {a.x, a.y, a.z, a.w};
#pragma unroll
            for (int j = 0; j < TNV; ++j) {
                float4 b = *(const float4*)&Bs[kk][tn * 4 + 64 * j];
                float bv[4] = {b.x, b.y, b.z, b.w};
#pragma unroll
                for (int r = 0; r < 4; ++r)
#pragma unroll
                    for (int c = 0; c < 4; ++c)
                        acc[r][c + j * 4] += av[r] * bv[c];
            }
        }
        __syncthreads();
    }
#pragma unroll
    for (int r = 0; r < 4; ++r) {
        int gm = m0 + tm * 4 + r;
        if (gm >= M) continue;
#pragma unroll
        for (int j = 0; j < TNV; ++j)
#pragma unroll
            for (int c = 0; c < 4; ++c) {
                int gn = n0 + tn * 4 + 64 * j + c;
                if (gn < N) {
                    float v = acc[r][c + j * 4];
                    if (BIAS) v += bias[gn];
                    C[(long)gm * ldc + gn] = v;
                }
            }
    }
}

// ---------------- CSR gather-aggregate, 128-dim (float2 x 64 lanes) ----------------
// Unroll-8: 8 row-gathers + 8 dinv loads in flight per iteration (2-deep
// dependent gather chain; MLP at zero byte cost). Remainder ladder 4/2/1.
template<bool RELU_IN, bool BIAS>
__global__ __launch_bounds__(256) void k_aggregate(
    const float2* __restrict__ hw, const int* __restrict__ row_start,
    const int* __restrict__ csr_src, const float* __restrict__ dinv,
    const float* __restrict__ bias, float2* __restrict__ out)
{
    const int tid = threadIdx.x;
    const int node = blockIdx.x * 4 + (tid >> 6);
    if (node >= N_NODES) return;
    const int lane = tid & 63;

    float dt = dinv[node];
    float2 v = hw[(long)node * 64 + lane];
    if (RELU_IN) { v.x = fmaxf(v.x, 0.f); v.y = fmaxf(v.y, 0.f); }
    float2 acc = {0.f, 0.f};

    const int e1 = row_start[node + 1];
    int e = row_start[node];
    for (; e + 8 <= e1; e += 8) {
        int s[8];
#pragma unroll
        for (int q = 0; q < 8; ++q) s[q] = csr_src[e + q];
        float w[8];
#pragma unroll
        for (int q = 0; q < 8; ++q) w[q] = dinv[s[q]];
        float2 u[8];
#pragma unroll
        for (int q = 0; q < 8; ++q) u[q] = hw[(long)s[q] * 64 + lane];
#pragma unroll
        for (int q = 0; q < 8; ++q) {
            if (RELU_IN) { u[q].x = fmaxf(u[q].x, 0.f); u[q].y = fmaxf(u[q].y, 0.f); }
            acc.x += w[q] * u[q].x;
            acc.y += w[q] * u[q].y;
        }
    }
    for (; e + 4 <= e1; e += 4) {
        int s0 = csr_src[e],     s1 = csr_src[e + 1];
        int s2 = csr_src[e + 2], s3 = csr_src[e + 3];
        float w0 = dinv[s0], w1 = dinv[s1], w2 = dinv[s2], w3 = dinv[s3];
        float2 u0 = hw[(long)s0 * 64 + lane];
        float2 u1 = hw[(long)s1 * 64 + lane];
        float2 u2 = hw[(long)s2 * 64 + lane];
        float2 u3 = hw[(long)s3 * 64 + lane];
        if (RELU_IN) {
            u0.x = fmaxf(u0.x, 0.f); u0.y = fmaxf(u0.y, 0.f);
            u1.x = fmaxf(u1.x, 0.f); u1.y = fmaxf(u1.y, 0.f);
            u2.x = fmaxf(u2.x, 0.f); u2.y = fmaxf(u2.y, 0.f);
            u3.x = fmaxf(u3.x, 0.f); u3.y = fmaxf(u3.y, 0.f);
        }
        acc.x += w0 * u0.x + w1 * u1.x + w2 * u2.x + w3 * u3.x;
        acc.y += w0 * u0.y + w1 * u1.y + w2 * u2.y + w3 * u3.y;
    }
    for (; e + 2 <= e1; e += 2) {
        int s0 = csr_src[e], s1 = csr_src[e + 1];
        float w0 = dinv[s0], w1 = dinv[s1];
        float2 u0 = hw[(long)s0 * 64 + lane];
        float2 u1 = hw[(long)s1 * 64 + lane];
        if (RELU_IN) {
            u0.x = fmaxf(u0.x, 0.f); u0.y = fmaxf(u0.y, 0.f);
            u1.x = fmaxf(u1.x, 0.f); u1.y = fmaxf(u1.y, 0.f);
        }
        acc.x += w0 * u0.x + w1 * u1.x;
        acc.y += w0 * u0.y + w1 * u1.y;
    }
    if (e < e1) {
        int s0 = csr_src[e];
        float w0 = dinv[s0];
        float2 u0 = hw[(long)s0 * 64 + lane];
        if (RELU_IN) { u0.x = fmaxf(u0.x, 0.f); u0.y = fmaxf(u0.y, 0.f); }
        acc.x += w0 * u0.x;
        acc.y += w0 * u0.y;
    }

    float2 r;
    r.x = dt * (acc.x + dt * v.x);
    r.y = dt * (acc.y + dt * v.y);
    if (BIAS) {
        float2 b = ((const float2*)bias)[lane];
        r.x += b.x; r.y += b.y;
    }
    out[(long)node * 64 + lane] = r;
}

// ---------------- CSR gather-aggregate, 47-dim (projected layer 3) ----------------
// hw rows padded to 48 floats (192 B = 3 aligned cache lines per gather).
__global__ __launch_bounds__(256) void k_aggregate47(
    const float* __restrict__ hw, const int* __restrict__ row_start,
    const int* __restrict__ csr_src, const float* __restrict__ dinv,
    const float* __restrict__ bias, float* __restrict__ out)
{
    const int tid = threadIdx.x;
    const int node = blockIdx.x * 4 + (tid >> 6);
    if (node >= N_NODES) return;
    const int lane = tid & 63;
    if (lane >= OUT_C) return;   // no barriers below; pad column 47 never touched

    float dt = dinv[node];
    float v = hw[(long)node * 48 + lane];
    float acc = 0.f;

    const int e1 = row_start[node + 1];
    int e = row_start[node];
    for (; e + 4 <= e1; e += 4) {
        int s0 = csr_src[e],     s1 = csr_src[e + 1];
        int s2 = csr_src[e + 2], s3 = csr_src[e + 3];
        float w0 = dinv[s0], w1 = dinv[s1], w2 = dinv[s2], w3 = dinv[s3];
        float u0 = hw[(long)s0 * 48 + lane];
        float u1 = hw[(long)s1 * 48 + lane];
        float u2 = hw[(long)s2 * 48 + lane];
        float u3 = hw[(long)s3 * 48 + lane];
        acc += w0 * u0 + w1 * u1 + w2 * u2 + w3 * u3;
    }
    for (; e + 2 <= e1; e += 2) {
        int s0 = csr_src[e], s1 = csr_src[e + 1];
        float w0 = dinv[s0], w1 = dinv[s1];
        float u0 = hw[(long)s0 * 48 + lane];
        float u1 = hw[(long)s1 * 48 + lane];
        acc += w0 * u0 + w1 * u1;
    }
    if (e < e1) {
        int s0 = csr_src[e];
        acc += dinv[s0] * hw[(long)s0 * 48 + lane];
    }

    out[(long)node * OUT_C + lane] = dt * (acc + dt * v) + bias[lane];
}

extern "C" void kernel_launch(void* const* d_in, const int* in_sizes, int n_in,
                              void* d_out, int out_size, void* d_ws, size_t ws_size,
                              hipStream_t stream) {
    const float* x  = (const float*)d_in[0];
    const int*   ei = (const int*)  d_in[1];
    const float* W1 = (const float*)d_in[2];
    const float* b1 = (const float*)d_in[3];
    const float* W2 = (const float*)d_in[4];
    const float* b2 = (const float*)d_in[5];
    const float* W3 = (const float*)d_in[6];
    const float* b3 = (const float*)d_in[7];
    float* out = (float*)d_out;
    const int* src = ei;
    const int* dst = ei + N_EDGES;

    char* ws = (char*)d_ws;
    float* dinv      = (float*)(ws + 0);
    int*   cnt       = (int*)  (ws + 200192);
    int*   cursor    = (int*)  (ws + 400384);
    int*   row_start = (int*)  (ws + 600576);
    int*   csr_src   = (int*)  (ws + 801280);
    float* bufA      = (float*)(ws + 7201280);
    float* bufB      = (float*)(ws + 32801280);
    u16*   W1Thi     = (u16*)  (ws + 58401280);   // 128*1440*2 = 368640
    u16*   W1Tlo     = (u16*)  (ws + 58769920);
    u16*   W2Thi     = (u16*)  (ws + 59138560);   // 128*128*2 = 32768
    u16*   W2Tlo     = (u16*)  (ws + 59171328);   // ends 59204096 (~59.2 MB)

    dim3 blk(256);
    const int gN  = (N_NODES + 255) / 256;
    const int gE  = (N_EDGES + 255) / 256;
    const int gAg = (N_NODES + 3) / 4;
    const int gMf = (N_NODES + 63) / 64;          // 782 blocks, 2/CU (80 KB LDS)
    dim3 gGemm((N_NODES + 63) / 64, 1);

    // ---- CSR build + norm ----
    k_zero_i<<<gN, blk, 0, stream>>>(cnt, N_NODES);
    k_zero_i<<<gN, blk, 0, stream>>>(cursor, N_NODES);
    k_count<<<gE, blk, 0, stream>>>(dst, cnt);
    k_dinv<<<gN, blk, 0, stream>>>(cnt, dinv);
    k_scan<<<1, 1024, 0, stream>>>(cnt, row_start);
    k_fill<<<gE, blk, 0, stream>>>(src, dst, row_start, cursor, csr_src);

    // ---- weight split/transpose ----
    k_wsplit<<<(128 * KPAD1 + 255) / 256, blk, 0, stream>>>(W1, IN_C, KPAD1, W1Thi, W1Tlo);
    k_wsplit<<<(128 * HID_C + 255) / 256, blk, 0, stream>>>(W2, HID_C, HID_C, W2Thi, W2Tlo);

    // ---- layer 1 ----
    k_gemm_mfma<false><<<gMf, blk, 0, stream>>>(x, W1Thi, W1Tlo, bufA, N_NODES, IN_C, KPAD1, IN_C);
    k_aggregate<false, true><<<gAg, blk, 0, stream>>>(
        (const float2*)bufA, row_start, csr_src, dinv, b1, (float2*)bufB);

    // ---- layer 2 ----
    k_gemm_mfma<true><<<gMf, blk, 0, stream>>>(bufB, W2Thi, W2Tlo, bufA, N_NODES, HID_C, HID_C, HID_C);
    k_aggregate<false, true><<<gAg, blk, 0, stream>>>(
        (const float2*)bufA, row_start, csr_src, dinv, b2, (float2*)bufB);

    // ---- layer 3: project first (A·(relu(h2)W3) == (A·relu(h2))W3), then 47-dim aggregate ----
    k_gemm<64, true, false><<<gGemm, blk, 0, stream>>>(
        bufB, W3, nullptr, bufA, N_NODES, OUT_C, HID_C, HID_C, OUT_C, 48);
    k_aggregate47<<<gAg, blk, 0, stream>>>(
        bufA, row_start, csr_src, dinv, b3, out);
}

// Round 10
// 691.499 us; speedup vs baseline: 1.1226x; 1.0048x over previous
//
#include <hip/hip_runtime.h>
#include <math.h>
#include <stdint.h>

#define N_NODES 50000
#define N_EDGES 1600000
#define IN_C    1433
#define HID_C   128
#define OUT_C   47
#define KPAD1   1440

typedef unsigned short u16;

// float -> bf16 (RNE), also returns the bf16 value re-expanded to float
__device__ inline u16 f2bf(float x, float& hf) {
    unsigned u = __float_as_uint(x);
    unsigned r = (u + 0x7FFFu + ((u >> 16) & 1u)) & 0xFFFF0000u;
    hf = __uint_as_float(r);
    return (u16)(r >> 16);
}

// async global->LDS, 16B per lane. LDS dest = wave-uniform base + lane*16;
// global src is per-lane (so swizzles are applied on the SOURCE address).
__device__ inline void gld_lds16(const void* g, const void* lds) {
    __builtin_amdgcn_global_load_lds(
        (const __attribute__((address_space(1))) unsigned int*)(unsigned long long)(uintptr_t)g,
        (__attribute__((address_space(3))) unsigned int*)(unsigned long long)(unsigned)(uintptr_t)lds,
        16, 0, 0);
}

__device__ inline void wg_barrier() {
    asm volatile("" ::: "memory");
    __builtin_amdgcn_s_barrier();
    asm volatile("" ::: "memory");
}

// ---------------- utility ----------------
__global__ __launch_bounds__(256) void k_zero_i(int* p, int n) {
    int i = blockIdx.x * 256 + threadIdx.x;
    if (i < n) p[i] = 0;
}

__global__ __launch_bounds__(256) void k_count(const int* __restrict__ dst, int* __restrict__ cnt) {
    int e = blockIdx.x * 256 + threadIdx.x;
    if (e < N_EDGES) atomicAdd(&cnt[dst[e]], 1);
}

__global__ __launch_bounds__(256) void k_dinv(const int* __restrict__ cnt, float* __restrict__ dinv) {
    int i = blockIdx.x * 256 + threadIdx.x;
    if (i < N_NODES) dinv[i] = rsqrtf(1.0f + (float)cnt[i]);
}

__global__ __launch_bounds__(1024) void k_scan(const int* __restrict__ cnt, int* __restrict__ row_start) {
    __shared__ int sums[1024];
    const int t = threadIdx.x;
    const int CH = (N_NODES + 1023) / 1024;
    const int base = t * CH;
    int s = 0;
    for (int j = 0; j < CH; ++j) { int idx = base + j; if (idx < N_NODES) s += cnt[idx]; }
    sums[t] = s;
    __syncthreads();
    for (int off = 1; off < 1024; off <<= 1) {
        int v = (t >= off) ? sums[t - off] : 0;
        __syncthreads();
        sums[t] += v;
        __syncthreads();
    }
    int run = (t == 0) ? 0 : sums[t - 1];
    for (int j = 0; j < CH; ++j) {
        int idx = base + j;
        if (idx < N_NODES) { row_start[idx] = run; run += cnt[idx]; }
    }
    if (t == 1023) row_start[N_NODES] = N_EDGES;
}

__global__ __launch_bounds__(256) void k_fill(
    const int* __restrict__ src, const int* __restrict__ dst,
    const int* __restrict__ row_start, int* __restrict__ cursor,
    int* __restrict__ csr_src)
{
    int e = blockIdx.x * 256 + threadIdx.x;
    if (e >= N_EDGES) return;
    int t = dst[e];
    int pos = row_start[t] + atomicAdd(&cursor[t], 1);
    csr_src[pos] = src[e];
}

// W [K][N=128] fp32 -> WT_hi/lo [128][Kpad] bf16 (zero-padded K)
__global__ __launch_bounds__(256) void k_wsplit(
    const float* __restrict__ W, int K, int Kpad,
    u16* __restrict__ Thi, u16* __restrict__ Tlo)
{
    int id = blockIdx.x * 256 + threadIdx.x;
    if (id >= 128 * Kpad) return;
    int n = id / Kpad, k = id - n * Kpad;
    float v = (k < K) ? W[(long)k * HID_C + n] : 0.f;
    float hf; u16 h = f2bf(v, hf);
    float d;  u16 l = f2bf(v - hf, d);
    Thi[id] = h; Tlo[id] = l;
}

// ---------------- depth-2 / 48 KB / 3-blocks-per-CU MFMA GEMM, N fixed = 128 ----------------
// C[M,128] = f(A)[M,K] @ B[K,128] via 3-term bf16 split (error ~2^-17).
// vs rounds 6/9: TLP experiment. 2-buffer rotation for A and B, counted
// vmcnt, LDS shrunk to exactly 48 KB -> 3 blocks/CU = 12 waves/CU (+50%
// TLP over the 72-80 KB variants). Per step: issue stage(t+1) into buf^1
// (prior readers finished at end-of-step barrier of t-1), vmcnt(6) (drains
// stage(t) only, stage(t+1) stays in flight ACROSS the barrier), barrier,
// compute, barrier. Never drains to 0 in the main loop.
template<bool RELU_A>
__global__ __launch_bounds__(256) void k_gemm_mfma(
    const float* __restrict__ A, const u16* __restrict__ BThi,
    const u16* __restrict__ BTlo, float* __restrict__ C,
    int M, int K, int Kpad, int lda)
{
    using bf16x8 = __attribute__((ext_vector_type(8))) short;
    using f32x4  = __attribute__((ext_vector_type(4))) float;

    __shared__ float Af[2][2048];   // [64 rows][32 k] fp32, 16B-chunk-swizzled (16 KB)
    __shared__ u16  Bhs[2][4096];   // [128 rows][32 k] bf16-hi, chunk-swizzled (16 KB)
    __shared__ u16  Bls[2][4096];   // [128 rows][32 k] bf16-lo (16 KB)

    const int tid  = threadIdx.x;
    const int wave = tid >> 6, lane = tid & 63;
    const int lr   = lane & 15, quad = lane >> 4;
    const int wm   = (wave >> 1) * 32, wn = (wave & 1) * 64;
    const int m0   = blockIdx.x * 64;

    f32x4 acc[2][4];
#pragma unroll
    for (int i = 0; i < 2; ++i)
#pragma unroll
        for (int j = 0; j < 4; ++j)
#pragma unroll
            for (int r = 0; r < 4; ++r) acc[i][j][r] = 0.f;

    const int nk = (K + 31) >> 5;

    // B slab for step t: 128 rows x 64 B (hi) + same (lo). 4 vmcnt ops/wave.
    // stored chunk g: row=g>>2, c=g&3 holds logical chunk q = c ^ ((row>>1)&3).
    auto stageB = [&](int t, int buf) {
        const int k0 = t * 32;
#pragma unroll
        for (int i = 0; i < 2; ++i) {
            const int gc  = wave * 128 + i * 64;
            const int g   = gc + lane;
            const int row = g >> 2, c = g & 3;
            const int q   = c ^ ((row >> 1) & 3);
            const long goff = (long)row * Kpad + k0 + q * 8;
            gld_lds16(BThi + goff, &Bhs[buf][gc * 8]);
            gld_lds16(BTlo + goff, &Bls[buf][gc * 8]);
        }
    };
    // A slab for step t: 64 rows x 128 B fp32, 2 vmcnt ops/wave. stored chunk
    // g: row=g>>3, c=g&7 holds logical chunk q = c ^ (row&7). Ragged last step
    // falls back to predicated register staging (compiler's own vmcnt drain on
    // that one step; ends with lgkmcnt(0) since raw barriers don't auto-drain
    // LDS writes).
    auto stageA = [&](int t, int buf) {
        const int k0 = t * 32;
        if (k0 + 32 <= K) {
#pragma unroll
            for (int i = 0; i < 2; ++i) {
                const int gc  = wave * 128 + i * 64;
                const int g   = gc + lane;
                const int row = g >> 3, c = g & 7;
                const int q   = c ^ (row & 7);
                int gm = m0 + row; if (gm >= M) gm = M - 1;   // clamp: rows unstored
                gld_lds16(A + (long)gm * lda + k0 + q * 4, &Af[buf][gc * 4]);
            }
        } else {
#pragma unroll
            for (int i = 0; i < 2; ++i) {
                const int g   = wave * 128 + i * 64 + lane;
                const int row = g >> 3, c = g & 7;
                const int q   = c ^ (row & 7);
                int gm = m0 + row; if (gm >= M) gm = M - 1;
                const float* p = A + (long)gm * lda;
                const int kb = k0 + q * 4;
                float4 v;
                v.x = (kb + 0 < K) ? p[kb + 0] : 0.f;
                v.y = (kb + 1 < K) ? p[kb + 1] : 0.f;
                v.z = (kb + 2 < K) ? p[kb + 2] : 0.f;
                v.w = (kb + 3 < K) ? p[kb + 3] : 0.f;
                *(float4*)&Af[buf][g * 4] = v;
            }
            asm volatile("s_waitcnt lgkmcnt(0)" ::: "memory");
        }
    };

    // prologue: stage(0) only; stage(1) is issued inside step 0.
    stageA(0, 0); stageB(0, 0);

    for (int t = 0; t < nk; ++t) {
        const int buf = t & 1;
        if (t + 1 < nk) {
            stageA(t + 1, buf ^ 1);
            stageB(t + 1, buf ^ 1);
            // outstanding <= stage(t)[6] + stage(t+1)[6]; drain stage(t) only.
            asm volatile("s_waitcnt vmcnt(6)" ::: "memory");
        } else {
            asm volatile("s_waitcnt vmcnt(0)" ::: "memory");
        }
        wg_barrier();   // all waves' stage(t) complete -> buf readable

        // ---- A fragments from LDS, convert fp32 -> hi/lo bf16 in-register ----
        bf16x8 ah[2], al[2];
#pragma unroll
        for (int i = 0; i < 2; ++i) {
            const int row = wm + i * 16 + lr;
            const int rx  = row & 7;
            f32x4 x0 = *(const f32x4*)&Af[buf][row * 32 + (((2 * quad)     ^ rx) * 4)];
            f32x4 x1 = *(const f32x4*)&Af[buf][row * 32 + (((2 * quad + 1) ^ rx) * 4)];
            float a8[8] = {x0[0], x0[1], x0[2], x0[3], x1[0], x1[1], x1[2], x1[3]};
#pragma unroll
            for (int c = 0; c < 8; ++c) {
                float x = RELU_A ? fmaxf(a8[c], 0.f) : a8[c];
                float hf; u16 h = f2bf(x, hf);
                float d;  u16 l = f2bf(x - hf, d);
                ah[i][c] = (short)h; al[i][c] = (short)l;
            }
        }
        // ---- B fragments from LDS ----
        bf16x8 bh[4], bl[4];
#pragma unroll
        for (int j = 0; j < 4; ++j) {
            const int row = wn + j * 16 + lr;
            const int cs  = quad ^ ((row >> 1) & 3);
            bh[j] = *(const bf16x8*)&Bhs[buf][row * 32 + cs * 8];
            bl[j] = *(const bf16x8*)&Bls[buf][row * 32 + cs * 8];
        }
#pragma unroll
        for (int i = 0; i < 2; ++i)
#pragma unroll
            for (int j = 0; j < 4; ++j) {
                acc[i][j] = __builtin_amdgcn_mfma_f32_16x16x32_bf16(ah[i], bh[j], acc[i][j], 0, 0, 0);
                acc[i][j] = __builtin_amdgcn_mfma_f32_16x16x32_bf16(ah[i], bl[j], acc[i][j], 0, 0, 0);
                acc[i][j] = __builtin_amdgcn_mfma_f32_16x16x32_bf16(al[i], bh[j], acc[i][j], 0, 0, 0);
            }
        wg_barrier();   // all waves done reading buf -> reusable at t+2
    }

    // ---- store: C/D layout col=lane&15, row=quad*4+reg ----
#pragma unroll
    for (int i = 0; i < 2; ++i)
#pragma unroll
        for (int r = 0; r < 4; ++r) {
            int row = m0 + wm + i * 16 + quad * 4 + r;
            if (row < M) {
#pragma unroll
                for (int j = 0; j < 4; ++j)
                    C[(long)row * HID_C + wn + j * 16 + lr] = acc[i][j][r];
            }
        }
}

// ---------------- fp32 tiled GEMM (kept for the small 128x47 layer) ----------------
template<int BN, bool RELU_A, bool BIAS>
__global__ __launch_bounds__(256) void k_gemm(
    const float* __restrict__ A, const float* __restrict__ B,
    const float* __restrict__ bias, float* __restrict__ C,
    int M, int N, int K, int lda, int ldb, int ldc)
{
    constexpr int BM = 64, BK = 16;
    constexpr int TNV = BN / 64;
    __shared__ float As[BK][BM + 4];
    __shared__ float Bs[BK][BN];

    const int tid = threadIdx.x;
    const int tm = tid >> 4;
    const int tn = tid & 15;
    const int m0 = blockIdx.x * BM;
    const int n0 = blockIdx.y * BN;

    float acc[4][TNV * 4];
#pragma unroll
    for (int r = 0; r < 4; ++r)
#pragma unroll
        for (int c = 0; c < TNV * 4; ++c) acc[r][c] = 0.f;

    for (int k0 = 0; k0 < K; k0 += BK) {
        {
            int kk = tid & 15;
            int r0 = tid >> 4;
#pragma unroll
            for (int it = 0; it < 4; ++it) {
                int r = r0 + 16 * it;
                int gm = m0 + r, gk = k0 + kk;
                float v = 0.f;
                if (gm < M && gk < K) v = A[(long)gm * lda + gk];
                if (RELU_A) v = fmaxf(v, 0.f);
                As[kk][r] = v;
            }
        }
        {
            constexpr int KPP = 256 / BN;
            int n  = tid % BN;
            int kb = tid / BN;
#pragma unroll
            for (int it = 0; it < BK / KPP; ++it) {
                int kk = kb + KPP * it;
                int gk = k0 + kk, gn = n0 + n;
                float v = 0.f;
                if (gk < K && gn < N) v = B[(long)gk * ldb + gn];
                Bs[kk][n] = v;
            }
        }
        __syncthreads();
#pragma unroll
        for (int kk = 0; kk < BK; ++kk) {
            float4 a = *(const float4*)&As[kk][tm * 4];
            float av[4] = {a.x, a.y, a.z, a.w};
#pragma unroll
            for (int j = 0; j < TNV; ++j) {
                float4 b = *(const float4*)&Bs[kk][tn * 4 + 64 * j];
                float bv[4] = {b.x, b.y, b.z, b.w};
#pragma unroll
                for (int r = 0; r < 4; ++r)
#pragma unroll
                    for (int c = 0; c < 4; ++c)
                        acc[r][c + j * 4] += av[r] * bv[c];
            }
        }
        __syncthreads();
    }
#pragma unroll
    for (int r = 0; r < 4; ++r) {
        int gm = m0 + tm * 4 + r;
        if (gm >= M) continue;
#pragma unroll
        for (int j = 0; j < TNV; ++j)
#pragma unroll
            for (int c = 0; c < 4; ++c) {
                int gn = n0 + tn * 4 + 64 * j + c;
                if (gn < N) {
                    float v = acc[r][c + j * 4];
                    if (BIAS) v += bias[gn];
                    C[(long)gm * ldc + gn] = v;
                }
            }
    }
}

// ---------------- CSR gather-aggregate, 128-dim (float2 x 64 lanes) ----------------
// Unroll-8: 8 row-gathers + 8 dinv loads in flight per iteration (2-deep
// dependent gather chain; MLP at zero byte cost). Remainder ladder 4/2/1.
template<bool RELU_IN, bool BIAS>
__global__ __launch_bounds__(256) void k_aggregate(
    const float2* __restrict__ hw, const int* __restrict__ row_start,
    const int* __restrict__ csr_src, const float* __restrict__ dinv,
    const float* __restrict__ bias, float2* __restrict__ out)
{
    const int tid = threadIdx.x;
    const int node = blockIdx.x * 4 + (tid >> 6);
    if (node >= N_NODES) return;
    const int lane = tid & 63;

    float dt = dinv[node];
    float2 v = hw[(long)node * 64 + lane];
    if (RELU_IN) { v.x = fmaxf(v.x, 0.f); v.y = fmaxf(v.y, 0.f); }
    float2 acc = {0.f, 0.f};

    const int e1 = row_start[node + 1];
    int e = row_start[node];
    for (; e + 8 <= e1; e += 8) {
        int s[8];
#pragma unroll
        for (int q = 0; q < 8; ++q) s[q] = csr_src[e + q];
        float w[8];
#pragma unroll
        for (int q = 0; q < 8; ++q) w[q] = dinv[s[q]];
        float2 u[8];
#pragma unroll
        for (int q = 0; q < 8; ++q) u[q] = hw[(long)s[q] * 64 + lane];
#pragma unroll
        for (int q = 0; q < 8; ++q) {
            if (RELU_IN) { u[q].x = fmaxf(u[q].x, 0.f); u[q].y = fmaxf(u[q].y, 0.f); }
            acc.x += w[q] * u[q].x;
            acc.y += w[q] * u[q].y;
        }
    }
    for (; e + 4 <= e1; e += 4) {
        int s0 = csr_src[e],     s1 = csr_src[e + 1];
        int s2 = csr_src[e + 2], s3 = csr_src[e + 3];
        float w0 = dinv[s0], w1 = dinv[s1], w2 = dinv[s2], w3 = dinv[s3];
        float2 u0 = hw[(long)s0 * 64 + lane];
        float2 u1 = hw[(long)s1 * 64 + lane];
        float2 u2 = hw[(long)s2 * 64 + lane];
        float2 u3 = hw[(long)s3 * 64 + lane];
        if (RELU_IN) {
            u0.x = fmaxf(u0.x, 0.f); u0.y = fmaxf(u0.y, 0.f);
            u1.x = fmaxf(u1.x, 0.f); u1.y = fmaxf(u1.y, 0.f);
            u2.x = fmaxf(u2.x, 0.f); u2.y = fmaxf(u2.y, 0.f);
            u3.x = fmaxf(u3.x, 0.f); u3.y = fmaxf(u3.y, 0.f);
        }
        acc.x += w0 * u0.x + w1 * u1.x + w2 * u2.x + w3 * u3.x;
        acc.y += w0 * u0.y + w1 * u1.y + w2 * u2.y + w3 * u3.y;
    }
    for (; e + 2 <= e1; e += 2) {
        int s0 = csr_src[e], s1 = csr_src[e + 1];
        float w0 = dinv[s0], w1 = dinv[s1];
        float2 u0 = hw[(long)s0 * 64 + lane];
        float2 u1 = hw[(long)s1 * 64 + lane];
        if (RELU_IN) {
            u0.x = fmaxf(u0.x, 0.f); u0.y = fmaxf(u0.y, 0.f);
            u1.x = fmaxf(u1.x, 0.f); u1.y = fmaxf(u1.y, 0.f);
        }
        acc.x += w0 * u0.x + w1 * u1.x;
        acc.y += w0 * u0.y + w1 * u1.y;
    }
    if (e < e1) {
        int s0 = csr_src[e];
        float w0 = dinv[s0];
        float2 u0 = hw[(long)s0 * 64 + lane];
        if (RELU_IN) { u0.x = fmaxf(u0.x, 0.f); u0.y = fmaxf(u0.y, 0.f); }
        acc.x += w0 * u0.x;
        acc.y += w0 * u0.y;
    }

    float2 r;
    r.x = dt * (acc.x + dt * v.x);
    r.y = dt * (acc.y + dt * v.y);
    if (BIAS) {
        float2 b = ((const float2*)bias)[lane];
        r.x += b.x; r.y += b.y;
    }
    out[(long)node * 64 + lane] = r;
}

// ---------------- CSR gather-aggregate, 47-dim (projected layer 3) ----------------
// hw rows padded to 48 floats (192 B = 3 aligned cache lines per gather).
__global__ __launch_bounds__(256) void k_aggregate47(
    const float* __restrict__ hw, const int* __restrict__ row_start,
    const int* __restrict__ csr_src, const float* __restrict__ dinv,
    const float* __restrict__ bias, float* __restrict__ out)
{
    const int tid = threadIdx.x;
    const int node = blockIdx.x * 4 + (tid >> 6);
    if (node >= N_NODES) return;
    const int lane = tid & 63;
    if (lane >= OUT_C) return;   // no barriers below; pad column 47 never touched

    float dt = dinv[node];
    float v = hw[(long)node * 48 + lane];
    float acc = 0.f;

    const int e1 = row_start[node + 1];
    int e = row_start[node];
    for (; e + 4 <= e1; e += 4) {
        int s0 = csr_src[e],     s1 = csr_src[e + 1];
        int s2 = csr_src[e + 2], s3 = csr_src[e + 3];
        float w0 = dinv[s0], w1 = dinv[s1], w2 = dinv[s2], w3 = dinv[s3];
        float u0 = hw[(long)s0 * 48 + lane];
        float u1 = hw[(long)s1 * 48 + lane];
        float u2 = hw[(long)s2 * 48 + lane];
        float u3 = hw[(long)s3 * 48 + lane];
        acc += w0 * u0 + w1 * u1 + w2 * u2 + w3 * u3;
    }
    for (; e + 2 <= e1; e += 2) {
        int s0 = csr_src[e], s1 = csr_src[e + 1];
        float w0 = dinv[s0], w1 = dinv[s1];
        float u0 = hw[(long)s0 * 48 + lane];
        float u1 = hw[(long)s1 * 48 + lane];
        acc += w0 * u0 + w1 * u1;
    }
    if (e < e1) {
        int s0 = csr_src[e];
        acc += dinv[s0] * hw[(long)s0 * 48 + lane];
    }

    out[(long)node * OUT_C + lane] = dt * (acc + dt * v) + bias[lane];
}

extern "C" void kernel_launch(void* const* d_in, const int* in_sizes, int n_in,
                              void* d_out, int out_size, void* d_ws, size_t ws_size,
                              hipStream_t stream) {
    const float* x  = (const float*)d_in[0];
    const int*   ei = (const int*)  d_in[1];
    const float* W1 = (const float*)d_in[2];
    const float* b1 = (const float*)d_in[3];
    const float* W2 = (const float*)d_in[4];
    const float* b2 = (const float*)d_in[5];
    const float* W3 = (const float*)d_in[6];
    const float* b3 = (const float*)d_in[7];
    float* out = (float*)d_out;
    const int* src = ei;
    const int* dst = ei + N_EDGES;

    char* ws = (char*)d_ws;
    float* dinv      = (float*)(ws + 0);
    int*   cnt       = (int*)  (ws + 200192);
    int*   cursor    = (int*)  (ws + 400384);
    int*   row_start = (int*)  (ws + 600576);
    int*   csr_src   = (int*)  (ws + 801280);
    float* bufA      = (float*)(ws + 7201280);
    float* bufB      = (float*)(ws + 32801280);
    u16*   W1Thi     = (u16*)  (ws + 58401280);   // 128*1440*2 = 368640
    u16*   W1Tlo     = (u16*)  (ws + 58769920);
    u16*   W2Thi     = (u16*)  (ws + 59138560);   // 128*128*2 = 32768
    u16*   W2Tlo     = (u16*)  (ws + 59171328);   // ends 59204096 (~59.2 MB)

    dim3 blk(256);
    const int gN  = (N_NODES + 255) / 256;
    const int gE  = (N_EDGES + 255) / 256;
    const int gAg = (N_NODES + 3) / 4;
    const int gMf = (N_NODES + 63) / 64;          // 782 blocks, 3/CU (48 KB LDS)
    dim3 gGemm((N_NODES + 63) / 64, 1);

    // ---- CSR build + norm ----
    k_zero_i<<<gN, blk, 0, stream>>>(cnt, N_NODES);
    k_zero_i<<<gN, blk, 0, stream>>>(cursor, N_NODES);
    k_count<<<gE, blk, 0, stream>>>(dst, cnt);
    k_dinv<<<gN, blk, 0, stream>>>(cnt, dinv);
    k_scan<<<1, 1024, 0, stream>>>(cnt, row_start);
    k_fill<<<gE, blk, 0, stream>>>(src, dst, row_start, cursor, csr_src);

    // ---- weight split/transpose ----
    k_wsplit<<<(128 * KPAD1 + 255) / 256, blk, 0, stream>>>(W1, IN_C, KPAD1, W1Thi, W1Tlo);
    k_wsplit<<<(128 * HID_C + 255) / 256, blk, 0, stream>>>(W2, HID_C, HID_C, W2Thi, W2Tlo);

    // ---- layer 1 ----
    k_gemm_mfma<false><<<gMf, blk, 0, stream>>>(x, W1Thi, W1Tlo, bufA, N_NODES, IN_C, KPAD1, IN_C);
    k_aggregate<false, true><<<gAg, blk, 0, stream>>>(
        (const float2*)bufA, row_start, csr_src, dinv, b1, (float2*)bufB);

    // ---- layer 2 ----
    k_gemm_mfma<true><<<gMf, blk, 0, stream>>>(bufB, W2Thi, W2Tlo, bufA, N_NODES, HID_C, HID_C, HID_C);
    k_aggregate<false, true><<<gAg, blk, 0, stream>>>(
        (const float2*)bufA, row_start, csr_src, dinv, b2, (float2*)bufB);

    // ---- layer 3: project first (A·(relu(h2)W3) == (A·relu(h2))W3), then 47-dim aggregate ----
    k_gemm<64, true, false><<<gGemm, blk, 0, stream>>>(
        bufB, W3, nullptr, bufA, N_NODES, OUT_C, HID_C, HID_C, OUT_C, 48);
    k_aggregate47<<<gAg, blk, 0, stream>>>(
        bufA, row_start, csr_src, dinv, b3, out);
}